// Round 1
// baseline (101.803 us; speedup 1.0000x reference)
//
#include <hip/hip_runtime.h>
#include <hip/hip_bf16.h>

#define DIM 768
#define EPS 1e-8f

// ---------------- Kernel 0: prefix scan of lens + total pairs + zero out ----
__global__ __launch_bounds__(1024) void scan_kernel(
    const int* __restrict__ p_lens, const int* __restrict__ n_lens,
    int* __restrict__ p_off, int* __restrict__ n_off,
    int* __restrict__ total, float* __restrict__ out, int bs)
{
    __shared__ int sp[1024];
    __shared__ int sn[1024];
    __shared__ int st[1024];
    int tid = threadIdx.x;
    int p = (tid < bs) ? p_lens[tid] : 0;
    int n = (tid < bs) ? n_lens[tid] : 0;
    sp[tid] = p;
    sn[tid] = n;
    st[tid] = p * n;
    __syncthreads();
    // Hillis-Steele inclusive scan
    for (int off = 1; off < 1024; off <<= 1) {
        int vp = (tid >= off) ? sp[tid - off] : 0;
        int vn = (tid >= off) ? sn[tid - off] : 0;
        __syncthreads();
        sp[tid] += vp;
        sn[tid] += vn;
        __syncthreads();
    }
    if (tid < bs) {
        p_off[tid] = sp[tid] - p;   // exclusive
        n_off[tid] = sn[tid] - n;
    }
    // tree-reduce pair counts
    for (int s = 512; s > 0; s >>= 1) {
        if (tid < s) st[tid] += st[tid + s];
        __syncthreads();
    }
    if (tid == 0) {
        *total = st[0];
        *out = 0.0f;
    }
}

// ---------------- Kernel 1: per-example cosines + pair hinge sum ------------
__global__ __launch_bounds__(256) void triplet_kernel(
    const float* __restrict__ anchor, const float* __restrict__ positive,
    const float* __restrict__ negative,
    const int* __restrict__ p_lens, const int* __restrict__ n_lens,
    const int* __restrict__ p_off_arr, const int* __restrict__ n_off_arr,
    const int* __restrict__ total_ptr, float* __restrict__ out)
{
    const int b = blockIdx.x;
    const int tid = threadIdx.x;
    const int wave = tid >> 6;
    const int lane = tid & 63;

    __shared__ float sA[DIM];
    __shared__ float sCos[32];     // up to 12 pos + 12 neg
    __shared__ float sRed[4];
    __shared__ float sAnorm;

    const int pl = p_lens[b];
    const int nl = n_lens[b];
    const int po = p_off_arr[b];
    const int no = n_off_arr[b];

    // --- stage anchor row in LDS, accumulate squared norm ---
    const float4* a4 = (const float4*)(anchor + (size_t)b * DIM);
    float asq = 0.0f;
    for (int q = tid; q < DIM / 4; q += 256) {
        float4 v = a4[q];
        ((float4*)sA)[q] = v;
        asq += v.x * v.x + v.y * v.y + v.z * v.z + v.w * v.w;
    }
    #pragma unroll
    for (int s = 32; s > 0; s >>= 1) asq += __shfl_xor(asq, s);
    if (lane == 0) sRed[wave] = asq;
    __syncthreads();
    if (tid == 0) sAnorm = sqrtf(sRed[0] + sRed[1] + sRed[2] + sRed[3]);
    __syncthreads();
    const float an = sAnorm;

    // --- cosines: one wave per vector (pos first, then neg) ---
    const int nvec = pl + nl;
    for (int v = wave; v < nvec; v += 4) {
        const float* x = (v < pl)
            ? positive + (size_t)(po + v) * DIM
            : negative + (size_t)(no + (v - pl)) * DIM;
        const float4* x4 = (const float4*)x;
        float dot = 0.0f, nx = 0.0f;
        #pragma unroll
        for (int q = 0; q < 3; ++q) {
            float4 xv = x4[lane + 64 * q];
            float4 av = ((const float4*)sA)[lane + 64 * q];
            dot += av.x * xv.x + av.y * xv.y + av.z * xv.z + av.w * xv.w;
            nx  += xv.x * xv.x + xv.y * xv.y + xv.z * xv.z + xv.w * xv.w;
        }
        #pragma unroll
        for (int s = 32; s > 0; s >>= 1) {
            dot += __shfl_xor(dot, s);
            nx  += __shfl_xor(nx, s);
        }
        if (lane == 0) sCos[v] = dot / fmaxf(an * sqrtf(nx), EPS);
    }
    __syncthreads();

    // --- pair hinge sum: loss term = max(c_an - c_ap + 1, 0) ---
    const int pairs = pl * nl;
    float s = 0.0f;
    for (int t = tid; t < pairs; t += 256) {
        int j = t / nl;
        int k = t - j * nl;
        s += fmaxf(sCos[pl + k] - sCos[j] + 1.0f, 0.0f);
    }
    #pragma unroll
    for (int sh = 32; sh > 0; sh >>= 1) s += __shfl_xor(s, sh);
    if (lane == 0) sRed[wave] = s;
    __syncthreads();
    if (tid == 0) {
        float blk = sRed[0] + sRed[1] + sRed[2] + sRed[3];
        atomicAdd(out, blk / (float)(*total_ptr));
    }
}

extern "C" void kernel_launch(void* const* d_in, const int* in_sizes, int n_in,
                              void* d_out, int out_size, void* d_ws, size_t ws_size,
                              hipStream_t stream) {
    const float* anchor   = (const float*)d_in[0];
    const float* positive = (const float*)d_in[1];
    const float* negative = (const float*)d_in[2];
    const int*   p_lens   = (const int*)d_in[3];
    const int*   n_lens   = (const int*)d_in[4];
    float* out = (float*)d_out;

    const int bs = in_sizes[3];   // 1024

    int* p_off = (int*)d_ws;
    int* n_off = p_off + bs;
    int* total = n_off + bs;

    scan_kernel<<<1, 1024, 0, stream>>>(p_lens, n_lens, p_off, n_off, total, out, bs);
    triplet_kernel<<<bs, 256, 0, stream>>>(anchor, positive, negative,
                                           p_lens, n_lens, p_off, n_off, total, out);
}

// Round 2
// 100.265 us; speedup vs baseline: 1.0153x; 1.0153x over previous
//
#include <hip/hip_runtime.h>
#include <hip/hip_bf16.h>

#define DIM 768
#define EPS 1e-8f

// One block per example. Each block:
//  - stages its anchor row in LDS (+ squared norm)
//  - scans the (L2-resident) lens arrays for its segment offsets + total pairs
//  - computes cosines (one wave per pos/neg vector, float4-coalesced)
//  - accumulates the pair hinge sum, atomicAdd(out, partial/total)
__global__ __launch_bounds__(256) void triplet_fused(
    const float* __restrict__ anchor, const float* __restrict__ positive,
    const float* __restrict__ negative,
    const int* __restrict__ p_lens, const int* __restrict__ n_lens,
    float* __restrict__ out, int bs)
{
    const int b = blockIdx.x;
    const int tid = threadIdx.x;
    const int wave = tid >> 6;
    const int lane = tid & 63;

    __shared__ float sA[DIM];
    __shared__ float sCos[32];      // up to 12 pos + 12 neg
    __shared__ float sRedF[4];
    __shared__ int   sRedI[4][3];
    __shared__ float sAnorm;
    __shared__ int   sPO, sNO, sTot;

    // ---- stage anchor row in LDS, accumulate squared norm ----
    const float4* a4 = (const float4*)(anchor + (size_t)b * DIM);
    float asq = 0.0f;
    for (int q = tid; q < DIM / 4; q += 256) {
        float4 v = a4[q];
        ((float4*)sA)[q] = v;
        asq += v.x * v.x + v.y * v.y + v.z * v.z + v.w * v.w;
    }

    // ---- inline scan of lens: exclusive offsets for b, total pair count ----
    int pre_p = 0, pre_n = 0, tot = 0;
    for (int i = tid; i < bs; i += 256) {
        int p = p_lens[i];
        int n = n_lens[i];
        if (i < b) { pre_p += p; pre_n += n; }
        tot += p * n;
    }

    #pragma unroll
    for (int s = 32; s > 0; s >>= 1) {
        asq   += __shfl_xor(asq, s);
        pre_p += __shfl_xor(pre_p, s);
        pre_n += __shfl_xor(pre_n, s);
        tot   += __shfl_xor(tot, s);
    }
    if (lane == 0) {
        sRedF[wave] = asq;
        sRedI[wave][0] = pre_p;
        sRedI[wave][1] = pre_n;
        sRedI[wave][2] = tot;
    }
    __syncthreads();
    if (tid == 0) {
        sAnorm = sqrtf(sRedF[0] + sRedF[1] + sRedF[2] + sRedF[3]);
        sPO  = sRedI[0][0] + sRedI[1][0] + sRedI[2][0] + sRedI[3][0];
        sNO  = sRedI[0][1] + sRedI[1][1] + sRedI[2][1] + sRedI[3][1];
        sTot = sRedI[0][2] + sRedI[1][2] + sRedI[2][2] + sRedI[3][2];
    }
    const int pl = p_lens[b];   // uniform address -> scalar load, L2 hit
    const int nl = n_lens[b];
    __syncthreads();
    const float an = sAnorm;
    const int po = sPO, no = sNO;

    // ---- cosines: one wave per vector (pos first, then neg) ----
    const int nvec = pl + nl;
    for (int v = wave; v < nvec; v += 4) {
        const float* x = (v < pl)
            ? positive + (size_t)(po + v) * DIM
            : negative + (size_t)(no + (v - pl)) * DIM;
        const float4* x4 = (const float4*)x;
        float dot = 0.0f, nx = 0.0f;
        #pragma unroll
        for (int q = 0; q < 3; ++q) {
            float4 xv = x4[lane + 64 * q];
            float4 av = ((const float4*)sA)[lane + 64 * q];
            dot += av.x * xv.x + av.y * xv.y + av.z * xv.z + av.w * xv.w;
            nx  += xv.x * xv.x + xv.y * xv.y + xv.z * xv.z + xv.w * xv.w;
        }
        #pragma unroll
        for (int s = 32; s > 0; s >>= 1) {
            dot += __shfl_xor(dot, s);
            nx  += __shfl_xor(nx, s);
        }
        if (lane == 0) sCos[v] = dot / fmaxf(an * sqrtf(nx), EPS);
    }
    __syncthreads();

    // ---- pair hinge sum: max(c_an - c_ap + 1, 0) ----
    const int pairs = pl * nl;
    float s = 0.0f;
    for (int t = tid; t < pairs; t += 256) {
        int j = t / nl;
        int k = t - j * nl;
        s += fmaxf(sCos[pl + k] - sCos[j] + 1.0f, 0.0f);
    }
    #pragma unroll
    for (int sh = 32; sh > 0; sh >>= 1) s += __shfl_xor(s, sh);
    if (lane == 0) sRedF[wave] = s;
    __syncthreads();
    if (tid == 0) {
        float blk = sRedF[0] + sRedF[1] + sRedF[2] + sRedF[3];
        atomicAdd(out, blk / (float)sTot);
    }
}

extern "C" void kernel_launch(void* const* d_in, const int* in_sizes, int n_in,
                              void* d_out, int out_size, void* d_ws, size_t ws_size,
                              hipStream_t stream) {
    const float* anchor   = (const float*)d_in[0];
    const float* positive = (const float*)d_in[1];
    const float* negative = (const float*)d_in[2];
    const int*   p_lens   = (const int*)d_in[3];
    const int*   n_lens   = (const int*)d_in[4];
    float* out = (float*)d_out;

    const int bs = in_sizes[3];   // 1024

    hipMemsetAsync(out, 0, sizeof(float), stream);
    triplet_fused<<<bs, 256, 0, stream>>>(anchor, positive, negative,
                                          p_lens, n_lens, out, bs);
}

// Round 3
// 91.877 us; speedup vs baseline: 1.1080x; 1.0913x over previous
//
#include <hip/hip_runtime.h>
#include <hip/hip_bf16.h>

#define DIM 768
#define EPS 1e-8f

// Kernel A: one block per example. Stages anchor in LDS, inline-scans the
// (L2-resident) lens arrays for segment offsets + total pairs, computes
// cosines (one wave per vector, float4-coalesced), accumulates pair hinge
// sum, and STORES the pre-divided partial to d_ws[b]. No atomics, no init.
__global__ __launch_bounds__(256) void triplet_partials(
    const float* __restrict__ anchor, const float* __restrict__ positive,
    const float* __restrict__ negative,
    const int* __restrict__ p_lens, const int* __restrict__ n_lens,
    float* __restrict__ partials, int bs)
{
    const int b = blockIdx.x;
    const int tid = threadIdx.x;
    const int wave = tid >> 6;
    const int lane = tid & 63;

    __shared__ float sA[DIM];
    __shared__ float sCos[32];      // up to 12 pos + 12 neg
    __shared__ float sRedF[4];
    __shared__ int   sRedI[4][3];
    __shared__ float sAnorm;
    __shared__ int   sPO, sNO, sTot;

    // ---- stage anchor row in LDS, accumulate squared norm ----
    const float4* a4 = (const float4*)(anchor + (size_t)b * DIM);
    float asq = 0.0f;
    for (int q = tid; q < DIM / 4; q += 256) {
        float4 v = a4[q];
        ((float4*)sA)[q] = v;
        asq += v.x * v.x + v.y * v.y + v.z * v.z + v.w * v.w;
    }

    // ---- inline scan of lens: exclusive offsets for b, total pair count ----
    int pre_p = 0, pre_n = 0, tot = 0;
    for (int i = tid; i < bs; i += 256) {
        int p = p_lens[i];
        int n = n_lens[i];
        if (i < b) { pre_p += p; pre_n += n; }
        tot += p * n;
    }

    #pragma unroll
    for (int s = 32; s > 0; s >>= 1) {
        asq   += __shfl_xor(asq, s);
        pre_p += __shfl_xor(pre_p, s);
        pre_n += __shfl_xor(pre_n, s);
        tot   += __shfl_xor(tot, s);
    }
    if (lane == 0) {
        sRedF[wave] = asq;
        sRedI[wave][0] = pre_p;
        sRedI[wave][1] = pre_n;
        sRedI[wave][2] = tot;
    }
    __syncthreads();
    if (tid == 0) {
        sAnorm = sqrtf(sRedF[0] + sRedF[1] + sRedF[2] + sRedF[3]);
        sPO  = sRedI[0][0] + sRedI[1][0] + sRedI[2][0] + sRedI[3][0];
        sNO  = sRedI[0][1] + sRedI[1][1] + sRedI[2][1] + sRedI[3][1];
        sTot = sRedI[0][2] + sRedI[1][2] + sRedI[2][2] + sRedI[3][2];
    }
    const int pl = p_lens[b];   // uniform -> scalar load, cache hit
    const int nl = n_lens[b];
    __syncthreads();
    const float an = sAnorm;
    const int po = sPO, no = sNO;

    // ---- cosines: one wave per vector (pos first, then neg) ----
    const int nvec = pl + nl;
    for (int v = wave; v < nvec; v += 4) {
        const float* x = (v < pl)
            ? positive + (size_t)(po + v) * DIM
            : negative + (size_t)(no + (v - pl)) * DIM;
        const float4* x4 = (const float4*)x;
        float dot = 0.0f, nx = 0.0f;
        #pragma unroll
        for (int q = 0; q < 3; ++q) {
            float4 xv = x4[lane + 64 * q];
            float4 av = ((const float4*)sA)[lane + 64 * q];
            dot += av.x * xv.x + av.y * xv.y + av.z * xv.z + av.w * xv.w;
            nx  += xv.x * xv.x + xv.y * xv.y + xv.z * xv.z + xv.w * xv.w;
        }
        #pragma unroll
        for (int s = 32; s > 0; s >>= 1) {
            dot += __shfl_xor(dot, s);
            nx  += __shfl_xor(nx, s);
        }
        if (lane == 0) sCos[v] = dot / fmaxf(an * sqrtf(nx), EPS);
    }
    __syncthreads();

    // ---- pair hinge sum: max(c_an - c_ap + 1, 0) ----
    const int pairs = pl * nl;
    float s = 0.0f;
    for (int t = tid; t < pairs; t += 256) {
        int j = t / nl;
        int k = t - j * nl;
        s += fmaxf(sCos[pl + k] - sCos[j] + 1.0f, 0.0f);
    }
    #pragma unroll
    for (int sh = 32; sh > 0; sh >>= 1) s += __shfl_xor(s, sh);
    if (lane == 0) sRedF[wave] = s;
    __syncthreads();
    if (tid == 0) {
        partials[b] = (sRedF[0] + sRedF[1] + sRedF[2] + sRedF[3]) / (float)sTot;
    }
}

// Kernel B: single block, deterministic reduce of the per-example partials.
__global__ __launch_bounds__(1024) void reduce_partials(
    const float* __restrict__ partials, float* __restrict__ out, int bs)
{
    const int tid = threadIdx.x;
    const int wave = tid >> 6;
    const int lane = tid & 63;
    __shared__ float sw[16];

    float v = (tid < bs) ? partials[tid] : 0.0f;
    #pragma unroll
    for (int s = 32; s > 0; s >>= 1) v += __shfl_xor(v, s);
    if (lane == 0) sw[wave] = v;
    __syncthreads();
    if (tid == 0) {
        float t = 0.0f;
        #pragma unroll
        for (int i = 0; i < 16; ++i) t += sw[i];
        *out = t;
    }
}

extern "C" void kernel_launch(void* const* d_in, const int* in_sizes, int n_in,
                              void* d_out, int out_size, void* d_ws, size_t ws_size,
                              hipStream_t stream) {
    const float* anchor   = (const float*)d_in[0];
    const float* positive = (const float*)d_in[1];
    const float* negative = (const float*)d_in[2];
    const int*   p_lens   = (const int*)d_in[3];
    const int*   n_lens   = (const int*)d_in[4];
    float* out = (float*)d_out;

    const int bs = in_sizes[3];   // 1024
    float* partials = (float*)d_ws;

    triplet_partials<<<bs, 256, 0, stream>>>(anchor, positive, negative,
                                             p_lens, n_lens, partials, bs);
    reduce_partials<<<1, 1024, 0, stream>>>(partials, out, bs);
}

// Round 6
// 90.644 us; speedup vs baseline: 1.1231x; 1.0136x over previous
//
#include <hip/hip_runtime.h>
#include <hip/hip_bf16.h>

#define DIM 768
#define EPS 1e-8f

// Kernel A: one block (512 thr = 8 waves) per example. Max occupancy:
// 4 blocks/CU = 32 waves/CU. Stages anchor in LDS, inline-scans the
// L2-resident lens arrays for segment offsets + total pairs, computes
// cosines (one wave per pos/neg vector, float4-coalesced, <=3 rounds),
// accumulates pair hinge sum, stores pre-divided partial. No atomics.
__global__ __launch_bounds__(512, 8) void triplet_partials(
    const float* __restrict__ anchor, const float* __restrict__ positive,
    const float* __restrict__ negative,
    const int* __restrict__ p_lens, const int* __restrict__ n_lens,
    float* __restrict__ partials, int bs)
{
    const int b = blockIdx.x;
    const int tid = threadIdx.x;
    const int wave = tid >> 6;
    const int lane = tid & 63;

    __shared__ float sA[DIM];
    __shared__ float sCos[32];      // up to 12 pos + 12 neg
    __shared__ float sRedF[8];
    __shared__ int   sRedI[8][3];
    __shared__ float sAnorm;
    __shared__ int   sPO, sNO, sTot;

    // ---- stage anchor row in LDS, accumulate squared norm ----
    const float4* a4 = (const float4*)(anchor + (size_t)b * DIM);
    float asq = 0.0f;
    for (int q = tid; q < DIM / 4; q += 512) {
        float4 v = a4[q];
        ((float4*)sA)[q] = v;
        asq += v.x * v.x + v.y * v.y + v.z * v.z + v.w * v.w;
    }

    // ---- inline scan of lens: exclusive offsets for b, total pair count ----
    int pre_p = 0, pre_n = 0, tot = 0;
    for (int i = tid; i < bs; i += 512) {
        int p = p_lens[i];
        int n = n_lens[i];
        if (i < b) { pre_p += p; pre_n += n; }
        tot += p * n;
    }

    #pragma unroll
    for (int s = 32; s > 0; s >>= 1) {
        asq   += __shfl_xor(asq, s);
        pre_p += __shfl_xor(pre_p, s);
        pre_n += __shfl_xor(pre_n, s);
        tot   += __shfl_xor(tot, s);
    }
    if (lane == 0) {
        sRedF[wave] = asq;
        sRedI[wave][0] = pre_p;
        sRedI[wave][1] = pre_n;
        sRedI[wave][2] = tot;
    }
    __syncthreads();
    if (tid == 0) {
        float a = 0.0f; int o0 = 0, o1 = 0, o2 = 0;
        #pragma unroll
        for (int w = 0; w < 8; ++w) {
            a  += sRedF[w];
            o0 += sRedI[w][0];
            o1 += sRedI[w][1];
            o2 += sRedI[w][2];
        }
        sAnorm = sqrtf(a);
        sPO = o0; sNO = o1; sTot = o2;
    }
    const int pl = p_lens[b];   // uniform -> scalar load, cache hit
    const int nl = n_lens[b];
    __syncthreads();
    const float an = sAnorm;
    const int po = sPO, no = sNO;

    // ---- cosines: one wave per vector (pos first, then neg) ----
    const int nvec = pl + nl;
    for (int v = wave; v < nvec; v += 8) {
        const float* x = (v < pl)
            ? positive + (size_t)(po + v) * DIM
            : negative + (size_t)(no + (v - pl)) * DIM;
        const float4* x4 = (const float4*)x;
        float dot = 0.0f, nx = 0.0f;
        #pragma unroll
        for (int q = 0; q < 3; ++q) {
            float4 xv = x4[lane + 64 * q];
            float4 av = ((const float4*)sA)[lane + 64 * q];
            dot += av.x * xv.x + av.y * xv.y + av.z * xv.z + av.w * xv.w;
            nx  += xv.x * xv.x + xv.y * xv.y + xv.z * xv.z + xv.w * xv.w;
        }
        #pragma unroll
        for (int s = 32; s > 0; s >>= 1) {
            dot += __shfl_xor(dot, s);
            nx  += __shfl_xor(nx, s);
        }
        if (lane == 0) sCos[v] = dot / fmaxf(an * sqrtf(nx), EPS);
    }
    __syncthreads();

    // ---- pair hinge sum: max(c_an - c_ap + 1, 0) ----
    const int pairs = pl * nl;
    float s = 0.0f;
    for (int t = tid; t < pairs; t += 512) {
        int j = t / nl;
        int k = t - j * nl;
        s += fmaxf(sCos[pl + k] - sCos[j] + 1.0f, 0.0f);
    }
    #pragma unroll
    for (int sh = 32; sh > 0; sh >>= 1) s += __shfl_xor(s, sh);
    if (lane == 0) sRedF[wave] = s;
    __syncthreads();
    if (tid == 0) {
        float blk = 0.0f;
        #pragma unroll
        for (int w = 0; w < 8; ++w) blk += sRedF[w];
        partials[b] = blk / (float)sTot;
    }
}

// Kernel B: single block, deterministic reduce of the per-example partials.
__global__ __launch_bounds__(1024) void reduce_partials(
    const float* __restrict__ partials, float* __restrict__ out, int bs)
{
    const int tid = threadIdx.x;
    const int wave = tid >> 6;
    const int lane = tid & 63;
    __shared__ float sw[16];

    float v = (tid < bs) ? partials[tid] : 0.0f;
    #pragma unroll
    for (int s = 32; s > 0; s >>= 1) v += __shfl_xor(v, s);
    if (lane == 0) sw[wave] = v;
    __syncthreads();
    if (tid == 0) {
        float t = 0.0f;
        #pragma unroll
        for (int i = 0; i < 16; ++i) t += sw[i];
        *out = t;
    }
}

extern "C" void kernel_launch(void* const* d_in, const int* in_sizes, int n_in,
                              void* d_out, int out_size, void* d_ws, size_t ws_size,
                              hipStream_t stream) {
    const float* anchor   = (const float*)d_in[0];
    const float* positive = (const float*)d_in[1];
    const float* negative = (const float*)d_in[2];
    const int*   p_lens   = (const int*)d_in[3];
    const int*   n_lens   = (const int*)d_in[4];
    float* out = (float*)d_out;

    const int bs = in_sizes[3];   // 1024
    float* partials = (float*)d_ws;

    triplet_partials<<<bs, 512, 0, stream>>>(anchor, positive, negative,
                                             p_lens, n_lens, partials, bs);
    reduce_partials<<<1, 1024, 0, stream>>>(partials, out, bs);
}